// Round 4
// baseline (635.067 us; speedup 1.0000x reference)
//
#include <hip/hip_runtime.h>

#define NHEADS 16
#define DKV 128
#define BB 2
#define SS 2048
#define DD 2048

typedef __attribute__((ext_vector_type(8))) short bf16x8;
typedef __attribute__((ext_vector_type(4))) short bf16x4;
typedef __attribute__((ext_vector_type(4))) float f32x4;

__device__ __forceinline__ short f2bf(float x) {
  unsigned u = __builtin_bit_cast(unsigned, x);
  unsigned r = (u + 0x7fffu + ((u >> 16) & 1u)) >> 16;  // RTNE
  return (short)(unsigned short)r;
}
__device__ __forceinline__ float bf2f(short s) {
  unsigned u = ((unsigned)(unsigned short)s) << 16;
  return __builtin_bit_cast(float, u);
}
// pack two floats -> two bf16 in one u32 (low = a)
__device__ __forceinline__ unsigned pk2bf(float a, float b) {
#if __has_builtin(__builtin_amdgcn_cvt_pk_bf16_f32)
  typedef __attribute__((ext_vector_type(2))) __bf16 bf2_t;
  bf2_t r = __builtin_amdgcn_cvt_pk_bf16_f32(a, b);
  return __builtin_bit_cast(unsigned, r);
#else
  unsigned ua = __builtin_bit_cast(unsigned, a);
  unsigned ub = __builtin_bit_cast(unsigned, b);
  return ((ua + 0x8000u) >> 16) | ((ub + 0x8000u) & 0xffff0000u);
#endif
}

// async global->LDS, 16B per lane; LDS dst = wave-uniform base + lane*16
__device__ __forceinline__ void async16(const void* g, void* l) {
  __builtin_amdgcn_global_load_lds(
      (__attribute__((address_space(1))) void*)g,
      (__attribute__((address_space(3))) void*)l, 16, 0, 0);
}

// ============ fp32 -> bf16 convert (q_in) =================================
__global__ __launch_bounds__(256) void cvt_q(const float* __restrict__ x,
                                             short* __restrict__ y) {
  int idx = blockIdx.x * 256 + threadIdx.x;
  int g = idx * 8;
  float4 a = *(const float4*)(x + g);
  float4 b = *(const float4*)(x + g + 4);
  uint4 o = {pk2bf(a.x, a.y), pk2bf(a.z, a.w), pk2bf(b.x, b.y), pk2bf(b.z, b.w)};
  *(uint4*)(y + g) = o;
}

// ============ weight transpose: W[K][N] fp32 -> Wt[N][K] bf16 =============
__global__ __launch_bounds__(256) void transpose_w(
    const float* __restrict__ W, short* __restrict__ Wt, int K, int N) {
  __shared__ float T[32][33];
  const int nt = blockIdx.x * 32;
  const int kt = blockIdx.y * 32;
  const int tx = threadIdx.x & 31;
  const int ty = threadIdx.x >> 5;
#pragma unroll
  for (int i = 0; i < 4; ++i)
    T[ty + i * 8][tx] = W[(size_t)(kt + ty + i * 8) * N + nt + tx];
  __syncthreads();
#pragma unroll
  for (int i = 0; i < 4; ++i)
    Wt[(size_t)(nt + ty + i * 8) * K + kt + tx] = f2bf(T[tx][ty + i * 8]);
}

// ============ MFMA GEMM with async staging (unchanged from R3) ============
template <int AMODE>
__global__ __launch_bounds__(256) void gemm_as(
    const void* __restrict__ Ap, const short* __restrict__ Bt,
    const float* __restrict__ bias, void* __restrict__ Cp,
    int M, int N, int K, int KC, int cmode) {
  __shared__ __align__(16) short As[128 * 32];
  __shared__ __align__(16) short Bs[128 * 32];
  const int tid = threadIdx.x;
  const int bm = blockIdx.y * 128;
  const int bn = blockIdx.x * 128;
  const int kz = blockIdx.z;
  const int w = tid >> 6, lane = tid & 63;
  const int lm = lane & 15, q4 = lane >> 4;
  const int m0 = (w & 1) * 64, n0 = (w >> 1) * 64;

  f32x4 acc[4][4];
#pragma unroll
  for (int mi = 0; mi < 4; ++mi)
#pragma unroll
    for (int ni = 0; ni < 4; ++ni) acc[mi][ni] = (f32x4){0.f, 0.f, 0.f, 0.f};

  const int kbeg = kz * KC;
  const int kend = kbeg + KC;

  for (int k0 = kbeg; k0 < kend; k0 += 32) {
    __syncthreads();
    if (AMODE == 1) {
      const short* Ab = (const short*)Ap;
#pragma unroll
      for (int i = 0; i < 2; ++i) {
        int rA = (w * 2 + i) * 16 + (lane >> 2);
        int cA = (lane & 3) ^ (rA & 3);
        async16(Ab + (size_t)(bm + rA) * K + k0 + cA * 8, &As[(w * 2 + i) * 512]);
      }
    } else {
      const float* Af = (const float*)Ap;
      float4 av[4];
#pragma unroll
      for (int i = 0; i < 4; ++i) {
        int qd = tid + i * 256;
        int r = qd >> 3, cq = qd & 7;
        av[i] = *(const float4*)(Af + (size_t)(bm + r) * K + k0 + cq * 4);
      }
#pragma unroll
      for (int i = 0; i < 4; ++i) {
        int qd = tid + i * 256;
        int r = qd >> 3, cq = qd & 7;
        int ch = cq >> 1, hf = cq & 1;
        int pc = ch ^ (r & 3);
        bf16x4 t = {f2bf(av[i].x), f2bf(av[i].y), f2bf(av[i].z), f2bf(av[i].w)};
        *(bf16x4*)&As[r * 32 + pc * 8 + hf * 4] = t;
      }
    }
#pragma unroll
    for (int i = 0; i < 2; ++i) {
      int rB = (w * 2 + i) * 16 + (lane >> 2);
      int cB = (lane & 3) ^ (rB & 3);
      async16(Bt + (size_t)(bn + rB) * K + k0 + cB * 8, &Bs[(w * 2 + i) * 512]);
    }
    __syncthreads();

    bf16x8 af[4], bf[4];
#pragma unroll
    for (int mi = 0; mi < 4; ++mi)
      af[mi] = *(const bf16x8*)&As[(m0 + mi * 16 + lm) * 32 + ((q4 ^ (lm & 3)) * 8)];
#pragma unroll
    for (int ni = 0; ni < 4; ++ni)
      bf[ni] = *(const bf16x8*)&Bs[(n0 + ni * 16 + lm) * 32 + ((q4 ^ (lm & 3)) * 8)];
#pragma unroll
    for (int mi = 0; mi < 4; ++mi)
#pragma unroll
      for (int ni = 0; ni < 4; ++ni)
        acc[mi][ni] = __builtin_amdgcn_mfma_f32_16x16x32_bf16(
            af[mi], bf[ni], acc[mi][ni], 0, 0, 0);
  }

  if (cmode == 2) {
    float* Cf = (float*)Cp + (size_t)kz * M * N;
#pragma unroll
    for (int mi = 0; mi < 4; ++mi)
#pragma unroll
      for (int ni = 0; ni < 4; ++ni)
#pragma unroll
        for (int reg = 0; reg < 4; ++reg)
          Cf[(size_t)(bm + m0 + mi * 16 + q4 * 4 + reg) * N +
             (bn + n0 + ni * 16 + lm)] = acc[mi][ni][reg];
  } else {
#pragma unroll
    for (int mi = 0; mi < 4; ++mi)
#pragma unroll
      for (int ni = 0; ni < 4; ++ni)
#pragma unroll
        for (int reg = 0; reg < 4; ++reg) {
          int rowg = bm + m0 + mi * 16 + q4 * 4 + reg;
          int colg = bn + n0 + ni * 16 + lm;
          float val = acc[mi][ni][reg] + bias[colg];
          if (cmode == 0)
            ((float*)Cp)[(size_t)rowg * N + colg] = val;
          else
            ((short*)Cp)[(size_t)rowg * N + colg] = f2bf(val);
        }
  }
}

// ============ KV reduce + bias + K-RoPE + V-transpose =====================
#define SPLITK 4
__global__ __launch_bounds__(256) void kv_reduce(
    const float* __restrict__ kpart, const float* __restrict__ vpart,
    const float* __restrict__ bk, const float* __restrict__ bv,
    short* __restrict__ kp, short* __restrict__ vtb) {
  __shared__ float Kt[64][128];
  __shared__ short Vl[128][68];
  const int tid = threadIdx.x;
  const int r0 = blockIdx.x * 64;
#pragma unroll
  for (int i = 0; i < 32; ++i) {
    int e = tid + i * 256;
    int r = e >> 7, c = e & 127;
    float sk = 0.f, sv = 0.f;
#pragma unroll
    for (int z = 0; z < SPLITK; ++z) {
      sk += kpart[((size_t)z * 4096 + r0 + r) * 128 + c];
      sv += vpart[((size_t)z * 4096 + r0 + r) * 128 + c];
    }
    Kt[r][c] = sk + bk[c];
    Vl[c][r] = f2bf(sv + bv[c]);
  }
  __syncthreads();
#pragma unroll
  for (int i = 0; i < 16; ++i) {
    int e = tid + i * 256;
    int r = e >> 6, d = e & 63;
    float x1 = Kt[r][d], x2 = Kt[r][d + 64];
    float s = (float)((r0 + r) & (SS - 1));
    float ang = s * powf(10000.0f, -(float)d * (1.0f / 64.0f));
    float sn, cs;
    sincosf(ang, &sn, &cs);
    kp[(size_t)(r0 + r) * 128 + d] = f2bf(x1 * cs - x2 * sn);
    kp[(size_t)(r0 + r) * 128 + d + 64] = f2bf(x1 * sn + x2 * cs);
  }
  const int b = r0 >> 11;
  const int j = tid >> 1, soff = (tid & 1) * 32;
  short* dst = vtb + ((size_t)b * 128 + j) * SS + (r0 & (SS - 1)) + soff;
#pragma unroll
  for (int t = 0; t < 4; ++t) {
    bf16x8 tmp;
#pragma unroll
    for (int u = 0; u < 8; ++u) tmp[u] = Vl[j][soff + t * 8 + u];
    *(bf16x8*)(dst + t * 8) = tmp;
  }
}

// ============ flash attention v3: S^T/O^T, V-from-global, b64 P ==========
// grid (16, H, B), 256 thr = 4 waves; wave owns 32 q-rows (2 ni tiles).
// S^T = mfma(A=K_lds, B=Q_regs); O^T = mfma(A=V^T_global, B=P^T_lds).
// l via ones-row MFMA. LDS: Ks[64][128] swizzled + per-wave Ps[32][72].
__global__ __launch_bounds__(256, 3) void flash_kernel(
    const short* __restrict__ q, const short* __restrict__ k,
    const short* __restrict__ vt, const unsigned char* __restrict__ mask,
    short* __restrict__ out) {
  __shared__ __align__(16) short Ks[64 * 128];
  __shared__ __align__(16) short Ps[4][32 * 72];
  __shared__ float Ms[64];
  const int qx = (int)gridDim.x - 1 - (int)blockIdx.x;  // heavy blocks first
  const int h = blockIdx.y, b = blockIdx.z;
  const int tid = threadIdx.x;
  const int w = tid >> 6, lane = tid & 63;
  const int lm = lane & 15, q4 = lane >> 4;
  const int qbase_row = qx * 128 + w * 32;

  // ---- Q fragments + RoPE, pre-scaled by 1/sqrt(dk) ----
  const float SCL = 0.08838834764831845f;
  bf16x8 qf[2][4];
#pragma unroll
  for (int ni = 0; ni < 2; ++ni) {
    const int srow = qbase_row + ni * 16 + lm;
    const short* qb = q + ((size_t)b * SS + srow) * (NHEADS * DKV) + h * DKV;
    float xv[4][8];
#pragma unroll
    for (int ks = 0; ks < 4; ++ks) {
      bf16x8 raw = *(const bf16x8*)(qb + ks * 32 + q4 * 8);
#pragma unroll
      for (int j = 0; j < 8; ++j) xv[ks][j] = bf2f(raw[j]);
    }
#pragma unroll
    for (int ks = 0; ks < 2; ++ks)
#pragma unroll
      for (int j = 0; j < 8; ++j) {
        int d = ks * 32 + q4 * 8 + j;
        float ang = (float)srow * powf(10000.0f, -(float)d * (1.0f / 64.0f));
        float sn, cs;
        sincosf(ang, &sn, &cs);
        float x1 = xv[ks][j], x2 = xv[ks + 2][j];
        qf[ni][ks][j] = f2bf((x1 * cs - x2 * sn) * SCL);
        qf[ni][ks + 2][j] = f2bf((x1 * sn + x2 * cs) * SCL);
      }
  }

  // ones A-fragment (row 0 only) for the l-accumulating MFMA
  bf16x8 vones;
  {
    short v = (lm == 0) ? (short)0x3F80 : (short)0;
#pragma unroll
    for (int j = 0; j < 8; ++j) vones[j] = v;
  }

  f32x4 O[8][2], Ol[2];
#pragma unroll
  for (int vi = 0; vi < 8; ++vi)
#pragma unroll
    for (int ni = 0; ni < 2; ++ni) O[vi][ni] = (f32x4){0.f, 0.f, 0.f, 0.f};
#pragma unroll
  for (int ni = 0; ni < 2; ++ni) Ol[ni] = (f32x4){0.f, 0.f, 0.f, 0.f};

  const int kmax = 2 * qx + 2;
  for (int kt = 0; kt < kmax; ++kt) {
    __syncthreads();  // waves done reading previous K tile
    // stage K tile [64][128] with 16B-chunk swizzle phys = c ^ (row&15)
#pragma unroll
    for (int i = 0; i < 4; ++i) {
      int r16 = i * 4 + (lane >> 4);
      int chunk = (lane & 15) ^ r16;
      async16(k + ((size_t)b * SS + kt * 64 + w * 16 + r16) * DKV + chunk * 8,
              &Ks[(w * 16 + i * 4) * 128]);
    }
    if (tid < 64) Ms[tid] = mask[(size_t)b * SS + kt * 64 + tid] ? -1e30f : 0.0f;
    __syncthreads();  // drains vmcnt + lds

    // ---- S^T = K Q^T : 4 key-tiles (m) x 2 q-tiles (n) x 4 k-steps ----
    f32x4 sacc[4][2];
#pragma unroll
    for (int mi = 0; mi < 4; ++mi)
#pragma unroll
      for (int ni = 0; ni < 2; ++ni) sacc[mi][ni] = (f32x4){0.f, 0.f, 0.f, 0.f};
#pragma unroll
    for (int mi = 0; mi < 4; ++mi)
#pragma unroll
      for (int ks = 0; ks < 4; ++ks) {
        bf16x8 kf = *(const bf16x8*)&Ks[(mi * 16 + lm) * 128 +
                                        (((ks * 4 + q4) ^ lm) << 3)];
#pragma unroll
        for (int ni = 0; ni < 2; ++ni)
          sacc[mi][ni] = __builtin_amdgcn_mfma_f32_16x16x32_bf16(
              kf, qf[ni][ks], sacc[mi][ni], 0, 0, 0);
      }

    // ---- exp + pack P^T (b64 per tile), causal only on diag tiles ----
    const bool diag = (kt >= 2 * qx);
#pragma unroll
    for (int mi = 0; mi < 4; ++mi) {
      f32x4 msv = *(const f32x4*)&Ms[mi * 16 + q4 * 4];
#pragma unroll
      for (int ni = 0; ni < 2; ++ni) {
        float pv[4];
#pragma unroll
        for (int reg = 0; reg < 4; ++reg) {
          float s = sacc[mi][ni][reg] + msv[reg];
          if (diag) {
            int kg = kt * 64 + mi * 16 + q4 * 4 + reg;
            int qg = qbase_row + ni * 16 + lm;
            if (kg > qg) s = -1e30f;
          }
          pv[reg] = __expf(s);
        }
        uint2 pkd = {pk2bf(pv[0], pv[1]), pk2bf(pv[2], pv[3])};
        *(uint2*)&Ps[w][(ni * 16 + lm) * 72 + mi * 16 + q4 * 4] = pkd;
      }
    }

    // ---- O^T += V^T P^T ; Ol row0 accumulates l = sum_k p ----
#pragma unroll
    for (int ks2 = 0; ks2 < 2; ++ks2) {
      bf16x8 pf[2];
#pragma unroll
      for (int ni = 0; ni < 2; ++ni) {
        pf[ni] = *(const bf16x8*)&Ps[w][(ni * 16 + lm) * 72 + ks2 * 32 + q4 * 8];
        Ol[ni] = __builtin_amdgcn_mfma_f32_16x16x32_bf16(vones, pf[ni], Ol[ni], 0, 0, 0);
      }
#pragma unroll
      for (int vi = 0; vi < 8; ++vi) {
        bf16x8 vf = *(const bf16x8*)(vt + ((size_t)b * DKV + vi * 16 + lm) * SS +
                                     kt * 64 + ks2 * 32 + q4 * 8);
#pragma unroll
        for (int ni = 0; ni < 2; ++ni)
          O[vi][ni] = __builtin_amdgcn_mfma_f32_16x16x32_bf16(
              vf, pf[ni], O[vi][ni], 0, 0, 0);
      }
    }
  }

  // ---- epilogue: broadcast l from C row 0 (lanes q4==0), scale, store ----
  float linv[2];
#pragma unroll
  for (int ni = 0; ni < 2; ++ni) {
    float lv = __shfl(Ol[ni][0], lm, 64);
    linv[ni] = 1.0f / lv;
  }
#pragma unroll
  for (int ni = 0; ni < 2; ++ni) {
    size_t orow =
        ((size_t)b * SS + qbase_row + ni * 16 + lm) * (NHEADS * DKV) + h * DKV;
#pragma unroll
    for (int vi = 0; vi < 8; ++vi) {
      float a0 = O[vi][ni][0] * linv[ni], a1 = O[vi][ni][1] * linv[ni];
      float a2 = O[vi][ni][2] * linv[ni], a3 = O[vi][ni][3] * linv[ni];
      uint2 pkd = {pk2bf(a0, a1), pk2bf(a2, a3)};
      *(uint2*)(out + orow + vi * 16 + q4 * 4) = pkd;
    }
  }
}

// ================= launch =================================================
extern "C" void kernel_launch(void* const* d_in, const int* in_sizes, int n_in,
                              void* d_out, int out_size, void* d_ws, size_t ws_size,
                              hipStream_t stream) {
  const float* q_in = (const float*)d_in[0];
  const float* k_in = (const float*)d_in[1];
  const float* v_in = (const float*)d_in[2];
  const unsigned char* mask = (const unsigned char*)d_in[3];
  const float* Wq = (const float*)d_in[4];
  const float* bq = (const float*)d_in[5];
  const float* Wk = (const float*)d_in[6];
  const float* bk = (const float*)d_in[7];
  const float* Wv = (const float*)d_in[8];
  const float* bv = (const float*)d_in[9];
  const float* Wo = (const float*)d_in[10];
  const float* bo = (const float*)d_in[11];

  const int M = BB * SS;  // 4096
  short* Wqt = (short*)d_ws;                   // [2048][2048]
  short* Wot = Wqt + (size_t)DD * DD;          // [2048][2048]
  short* Wkt = Wot + (size_t)DD * DD;          // [128][2048]
  short* Wvt = Wkt + (size_t)DKV * DD;         // [128][2048]
  short* qb  = Wvt + (size_t)DKV * DD;         // [4096][2048] bf16 (input)
  short* qp  = qb + (size_t)M * DD;            // [4096][2048] bf16 (Q proj)
  short* kp  = qp + (size_t)M * DD;            // [4096][128] bf16 (roped K)
  short* vtb = kp + (size_t)M * DKV;           // [2][128][2048] bf16 (V^T)
  float* kpart = (float*)(vtb + (size_t)BB * DKV * SS);  // [4][4096][128]
  float* vpart = kpart + (size_t)SPLITK * M * DKV;       // [4][4096][128]
  short* ap = qb;  // alias: qb dead after Q-proj; flash output reuses it

  cvt_q<<<M * DD / (8 * 256), 256, 0, stream>>>(q_in, qb);
  transpose_w<<<dim3(DD / 32, DD / 32), 256, 0, stream>>>(Wq, Wqt, DD, DD);
  transpose_w<<<dim3(DKV / 32, DD / 32), 256, 0, stream>>>(Wk, Wkt, DD, DKV);
  transpose_w<<<dim3(DKV / 32, DD / 32), 256, 0, stream>>>(Wv, Wvt, DD, DKV);
  transpose_w<<<dim3(DD / 32, DD / 32), 256, 0, stream>>>(Wo, Wot, DD, DD);

  gemm_as<1><<<dim3(DD / 128, M / 128, 1), 256, 0, stream>>>(
      qb, Wqt, bq, qp, M, DD, DD, DD, 1);
  gemm_as<0><<<dim3(1, M / 128, SPLITK), 256, 0, stream>>>(
      k_in, Wkt, nullptr, kpart, M, DKV, DD, DD / SPLITK, 2);
  gemm_as<0><<<dim3(1, M / 128, SPLITK), 256, 0, stream>>>(
      v_in, Wvt, nullptr, vpart, M, DKV, DD, DD / SPLITK, 2);
  kv_reduce<<<M / 64, 256, 0, stream>>>(kpart, vpart, bk, bv, kp, vtb);

  flash_kernel<<<dim3(SS / 128, NHEADS, BB), 256, 0, stream>>>(
      qp, kp, vtb, mask, ap);

  gemm_as<1><<<dim3(DD / 128, M / 128, 1), 256, 0, stream>>>(
      ap, Wot, bo, d_out, M, DD, DD, DD, 0);
}

// Round 5
// 520.142 us; speedup vs baseline: 1.2209x; 1.2209x over previous
//
#include <hip/hip_runtime.h>

#define NHEADS 16
#define DKV 128
#define BB 2
#define SS 2048
#define DD 2048

typedef __attribute__((ext_vector_type(8))) short bf16x8;
typedef __attribute__((ext_vector_type(4))) short bf16x4;
typedef __attribute__((ext_vector_type(4))) float f32x4;

__device__ __forceinline__ short f2bf(float x) {
  unsigned u = __builtin_bit_cast(unsigned, x);
  unsigned r = (u + 0x7fffu + ((u >> 16) & 1u)) >> 16;  // RTNE
  return (short)(unsigned short)r;
}
__device__ __forceinline__ float bf2f(short s) {
  unsigned u = ((unsigned)(unsigned short)s) << 16;
  return __builtin_bit_cast(float, u);
}
// pack two floats -> two bf16 in one u32 (low = a)
__device__ __forceinline__ unsigned pk2bf(float a, float b) {
#if __has_builtin(__builtin_amdgcn_cvt_pk_bf16_f32)
  typedef __attribute__((ext_vector_type(2))) __bf16 bf2_t;
  bf2_t r = __builtin_amdgcn_cvt_pk_bf16_f32(a, b);
  return __builtin_bit_cast(unsigned, r);
#else
  unsigned ua = __builtin_bit_cast(unsigned, a);
  unsigned ub = __builtin_bit_cast(unsigned, b);
  return ((ua + 0x8000u) >> 16) | ((ub + 0x8000u) & 0xffff0000u);
#endif
}

// async global->LDS, 16B per lane; LDS dst = wave-uniform base + lane*16
__device__ __forceinline__ void async16(const void* g, void* l) {
  __builtin_amdgcn_global_load_lds(
      (__attribute__((address_space(1))) void*)g,
      (__attribute__((address_space(3))) void*)l, 16, 0, 0);
}

// ============ fp32 -> bf16 convert (q_in) =================================
__global__ __launch_bounds__(256) void cvt_q(const float* __restrict__ x,
                                             short* __restrict__ y) {
  int idx = blockIdx.x * 256 + threadIdx.x;
  int g = idx * 8;
  float4 a = *(const float4*)(x + g);
  float4 b = *(const float4*)(x + g + 4);
  uint4 o = {pk2bf(a.x, a.y), pk2bf(a.z, a.w), pk2bf(b.x, b.y), pk2bf(b.z, b.w)};
  *(uint4*)(y + g) = o;
}

// ============ weight transpose: W[K][N] fp32 -> Wt[N][K] bf16 =============
__global__ __launch_bounds__(256) void transpose_w(
    const float* __restrict__ W, short* __restrict__ Wt, int K, int N) {
  __shared__ float T[32][33];
  const int nt = blockIdx.x * 32;
  const int kt = blockIdx.y * 32;
  const int tx = threadIdx.x & 31;
  const int ty = threadIdx.x >> 5;
#pragma unroll
  for (int i = 0; i < 4; ++i)
    T[ty + i * 8][tx] = W[(size_t)(kt + ty + i * 8) * N + nt + tx];
  __syncthreads();
#pragma unroll
  for (int i = 0; i < 4; ++i)
    Wt[(size_t)(nt + ty + i * 8) * K + kt + tx] = f2bf(T[tx][ty + i * 8]);
}

// ============ MFMA GEMM with async staging ================================
template <int AMODE>
__global__ __launch_bounds__(256) void gemm_as(
    const void* __restrict__ Ap, const short* __restrict__ Bt,
    const float* __restrict__ bias, void* __restrict__ Cp,
    int M, int N, int K, int KC, int cmode) {
  __shared__ __align__(16) short As[128 * 32];
  __shared__ __align__(16) short Bs[128 * 32];
  const int tid = threadIdx.x;
  const int bm = blockIdx.y * 128;
  const int bn = blockIdx.x * 128;
  const int kz = blockIdx.z;
  const int w = tid >> 6, lane = tid & 63;
  const int lm = lane & 15, q4 = lane >> 4;
  const int m0 = (w & 1) * 64, n0 = (w >> 1) * 64;

  f32x4 acc[4][4];
#pragma unroll
  for (int mi = 0; mi < 4; ++mi)
#pragma unroll
    for (int ni = 0; ni < 4; ++ni) acc[mi][ni] = (f32x4){0.f, 0.f, 0.f, 0.f};

  const int kbeg = kz * KC;
  const int kend = kbeg + KC;

  for (int k0 = kbeg; k0 < kend; k0 += 32) {
    __syncthreads();
    if (AMODE == 1) {
      const short* Ab = (const short*)Ap;
#pragma unroll
      for (int i = 0; i < 2; ++i) {
        int rA = (w * 2 + i) * 16 + (lane >> 2);
        int cA = (lane & 3) ^ (rA & 3);
        async16(Ab + (size_t)(bm + rA) * K + k0 + cA * 8, &As[(w * 2 + i) * 512]);
      }
    } else {
      const float* Af = (const float*)Ap;
      float4 av[4];
#pragma unroll
      for (int i = 0; i < 4; ++i) {
        int qd = tid + i * 256;
        int r = qd >> 3, cq = qd & 7;
        av[i] = *(const float4*)(Af + (size_t)(bm + r) * K + k0 + cq * 4);
      }
#pragma unroll
      for (int i = 0; i < 4; ++i) {
        int qd = tid + i * 256;
        int r = qd >> 3, cq = qd & 7;
        int ch = cq >> 1, hf = cq & 1;
        int pc = ch ^ (r & 3);
        bf16x4 t = {f2bf(av[i].x), f2bf(av[i].y), f2bf(av[i].z), f2bf(av[i].w)};
        *(bf16x4*)&As[r * 32 + pc * 8 + hf * 4] = t;
      }
    }
#pragma unroll
    for (int i = 0; i < 2; ++i) {
      int rB = (w * 2 + i) * 16 + (lane >> 2);
      int cB = (lane & 3) ^ (rB & 3);
      async16(Bt + (size_t)(bn + rB) * K + k0 + cB * 8, &Bs[(w * 2 + i) * 512]);
    }
    __syncthreads();

    bf16x8 af[4], bf[4];
#pragma unroll
    for (int mi = 0; mi < 4; ++mi)
      af[mi] = *(const bf16x8*)&As[(m0 + mi * 16 + lm) * 32 + ((q4 ^ (lm & 3)) * 8)];
#pragma unroll
    for (int ni = 0; ni < 4; ++ni)
      bf[ni] = *(const bf16x8*)&Bs[(n0 + ni * 16 + lm) * 32 + ((q4 ^ (lm & 3)) * 8)];
#pragma unroll
    for (int mi = 0; mi < 4; ++mi)
#pragma unroll
      for (int ni = 0; ni < 4; ++ni)
        acc[mi][ni] = __builtin_amdgcn_mfma_f32_16x16x32_bf16(
            af[mi], bf[ni], acc[mi][ni], 0, 0, 0);
  }

  if (cmode == 2) {
    float* Cf = (float*)Cp + (size_t)kz * M * N;
#pragma unroll
    for (int mi = 0; mi < 4; ++mi)
#pragma unroll
      for (int ni = 0; ni < 4; ++ni)
#pragma unroll
        for (int reg = 0; reg < 4; ++reg)
          Cf[(size_t)(bm + m0 + mi * 16 + q4 * 4 + reg) * N +
             (bn + n0 + ni * 16 + lm)] = acc[mi][ni][reg];
  } else {
#pragma unroll
    for (int mi = 0; mi < 4; ++mi)
#pragma unroll
      for (int ni = 0; ni < 4; ++ni)
#pragma unroll
        for (int reg = 0; reg < 4; ++reg) {
          int rowg = bm + m0 + mi * 16 + q4 * 4 + reg;
          int colg = bn + n0 + ni * 16 + lm;
          float val = acc[mi][ni][reg] + bias[colg];
          if (cmode == 0)
            ((float*)Cp)[(size_t)rowg * N + colg] = val;
          else
            ((short*)Cp)[(size_t)rowg * N + colg] = f2bf(val);
        }
  }
}

// ============ KV reduce + bias + K-RoPE + V-transpose =====================
#define SPLITK 4
__global__ __launch_bounds__(256) void kv_reduce(
    const float* __restrict__ kpart, const float* __restrict__ vpart,
    const float* __restrict__ bk, const float* __restrict__ bv,
    short* __restrict__ kp, short* __restrict__ vtb) {
  __shared__ float Kt[64][128];
  __shared__ short Vl[128][68];
  const int tid = threadIdx.x;
  const int r0 = blockIdx.x * 64;
#pragma unroll
  for (int i = 0; i < 32; ++i) {
    int e = tid + i * 256;
    int r = e >> 7, c = e & 127;
    float sk = 0.f, sv = 0.f;
#pragma unroll
    for (int z = 0; z < SPLITK; ++z) {
      sk += kpart[((size_t)z * 4096 + r0 + r) * 128 + c];
      sv += vpart[((size_t)z * 4096 + r0 + r) * 128 + c];
    }
    Kt[r][c] = sk + bk[c];
    Vl[c][r] = f2bf(sv + bv[c]);
  }
  __syncthreads();
#pragma unroll
  for (int i = 0; i < 16; ++i) {
    int e = tid + i * 256;
    int r = e >> 6, d = e & 63;
    float x1 = Kt[r][d], x2 = Kt[r][d + 64];
    float s = (float)((r0 + r) & (SS - 1));
    float ang = s * powf(10000.0f, -(float)d * (1.0f / 64.0f));
    float sn, cs;
    sincosf(ang, &sn, &cs);
    kp[(size_t)(r0 + r) * 128 + d] = f2bf(x1 * cs - x2 * sn);
    kp[(size_t)(r0 + r) * 128 + d + 64] = f2bf(x1 * sn + x2 * cs);
  }
  const int b = r0 >> 11;
  const int j = tid >> 1, soff = (tid & 1) * 32;
  short* dst = vtb + ((size_t)b * 128 + j) * SS + (r0 & (SS - 1)) + soff;
#pragma unroll
  for (int t = 0; t < 4; ++t) {
    bf16x8 tmp;
#pragma unroll
    for (int u = 0; u < 8; ++u) tmp[u] = Vl[j][soff + t * 8 + u];
    *(bf16x8*)(dst + t * 8) = tmp;
  }
}

// ============ flash attention v5 ==========================================
// R3 memory path (K+V async->LDS) + BQ=128 (32 q/wave) + S^T orientation
// (b64 P^T writes) + l via ones-B MFMA (no shuffles, no scalar adds).
// grid (S/128, H, B), 256 thr = 4 waves.
// LDS: Ks[64][128] swz(&7), Vs[128][64] swz(&7), per-wave Ps[32][72], Ms[64].
#define PSTR 72

__global__ __launch_bounds__(256, 3) void flash_kernel(
    const short* __restrict__ q, const short* __restrict__ k,
    const short* __restrict__ vt, const unsigned char* __restrict__ mask,
    short* __restrict__ out) {
  __shared__ __align__(16) short Ks[64 * 128];
  __shared__ __align__(16) short Vs[128 * 64];
  __shared__ __align__(16) short Ps[4][32 * PSTR];
  __shared__ float Ms[64];
  const int qx = (int)gridDim.x - 1 - (int)blockIdx.x;  // heavy blocks first
  const int h = blockIdx.y, b = blockIdx.z;
  const int tid = threadIdx.x;
  const int w = tid >> 6, lane = tid & 63;
  const int lm = lane & 15, q4 = lane >> 4;
  const int qbase_row = qx * 128 + w * 32;

  // ---- Q fragments + RoPE, pre-scaled by 1/sqrt(dk); B-operand rows n=lm --
  const float SCL = 0.08838834764831845f;
  bf16x8 qf[2][4];
#pragma unroll
  for (int ni = 0; ni < 2; ++ni) {
    const int srow = qbase_row + ni * 16 + lm;
    const short* qb = q + ((size_t)b * SS + srow) * (NHEADS * DKV) + h * DKV;
    float xv[4][8];
#pragma unroll
    for (int ks = 0; ks < 4; ++ks) {
      bf16x8 raw = *(const bf16x8*)(qb + ks * 32 + q4 * 8);
#pragma unroll
      for (int j = 0; j < 8; ++j) xv[ks][j] = bf2f(raw[j]);
    }
#pragma unroll
    for (int ks = 0; ks < 2; ++ks)
#pragma unroll
      for (int j = 0; j < 8; ++j) {
        int d = ks * 32 + q4 * 8 + j;
        float ang = (float)srow * powf(10000.0f, -(float)d * (1.0f / 64.0f));
        float sn, cs;
        sincosf(ang, &sn, &cs);
        float x1 = xv[ks][j], x2 = xv[ks + 2][j];
        qf[ni][ks][j] = f2bf((x1 * cs - x2 * sn) * SCL);
        qf[ni][ks + 2][j] = f2bf((x1 * sn + x2 * cs) * SCL);
      }
  }

  // all-ones B fragment: C[q][*] = sum_k P[q,k]  (l accumulator)
  bf16x8 onesb;
#pragma unroll
  for (int j = 0; j < 8; ++j) onesb[j] = (short)0x3F80;

  f32x4 O[8][2], Ol[2];
#pragma unroll
  for (int vi = 0; vi < 8; ++vi)
#pragma unroll
    for (int ni = 0; ni < 2; ++ni) O[vi][ni] = (f32x4){0.f, 0.f, 0.f, 0.f};
#pragma unroll
  for (int ni = 0; ni < 2; ++ni) Ol[ni] = (f32x4){0.f, 0.f, 0.f, 0.f};

  const int kmax = 2 * qx + 2;
  for (int kt = 0; kt < kmax; ++kt) {
    __syncthreads();  // waves done reading previous K/V tiles
    // K tile [64][128], swizzle phys_chunk = logical ^ (row&7)
#pragma unroll
    for (int i = 0; i < 4; ++i) {
      int rK = (w * 4 + i) * 4 + (lane >> 4);
      int cK = (lane & 15) ^ (rK & 7);
      async16(k + ((size_t)b * SS + kt * 64 + rK) * DKV + cK * 8,
              &Ks[(w * 4 + i) * 512]);
    }
    // V^T tile [128][64], swizzle phys_chunk = logical ^ (row&7)
#pragma unroll
    for (int i = 0; i < 4; ++i) {
      int rV = (w * 4 + i) * 8 + (lane >> 3);
      int cV = (lane & 7) ^ (rV & 7);
      async16(vt + ((size_t)b * DKV + rV) * SS + kt * 64 + cV * 8,
              &Vs[(w * 4 + i) * 512]);
    }
    if (tid < 64) Ms[tid] = mask[(size_t)b * SS + kt * 64 + tid] ? -1e30f : 0.0f;
    __syncthreads();  // drains vmcnt + lds

    // ---- S^T = K (Q*scl)^T : 4 key-tiles (m) x 2 q-tiles (n) x 4 k ----
    f32x4 sacc[4][2];
#pragma unroll
    for (int mi = 0; mi < 4; ++mi)
#pragma unroll
      for (int ni = 0; ni < 2; ++ni) sacc[mi][ni] = (f32x4){0.f, 0.f, 0.f, 0.f};
#pragma unroll
    for (int mi = 0; mi < 4; ++mi)
#pragma unroll
      for (int ks = 0; ks < 4; ++ks) {
        bf16x8 kf = *(const bf16x8*)&Ks[(mi * 16 + lm) * 128 +
                                        (((ks * 4 + q4) ^ (lm & 7)) << 3)];
#pragma unroll
        for (int ni = 0; ni < 2; ++ni)
          sacc[mi][ni] = __builtin_amdgcn_mfma_f32_16x16x32_bf16(
              kf, qf[ni][ks], sacc[mi][ni], 0, 0, 0);
      }

    // ---- exp + b64 P^T writes; causal only on last two tiles ----
    const bool diag = (kt >= 2 * qx);
#pragma unroll
    for (int mi = 0; mi < 4; ++mi) {
      f32x4 msv = *(const f32x4*)&Ms[mi * 16 + q4 * 4];
#pragma unroll
      for (int ni = 0; ni < 2; ++ni) {
        float pv[4];
#pragma unroll
        for (int reg = 0; reg < 4; ++reg) {
          float s = sacc[mi][ni][reg] + msv[reg];
          if (diag) {
            int kg = kt * 64 + mi * 16 + q4 * 4 + reg;
            int qg = qbase_row + ni * 16 + lm;
            if (kg > qg) s = -1e30f;
          }
          pv[reg] = __expf(s);
        }
        uint2 pkd = {pk2bf(pv[0], pv[1]), pk2bf(pv[2], pv[3])};
        *(uint2*)&Ps[w][(ni * 16 + lm) * PSTR + mi * 16 + q4 * 4] = pkd;
      }
    }

    // ---- O += P V (A=pf rows q, B=vf rows d); Ol accumulates l ----
#pragma unroll
    for (int ks2 = 0; ks2 < 2; ++ks2) {
      bf16x8 pf[2];
#pragma unroll
      for (int ni = 0; ni < 2; ++ni) {
        pf[ni] = *(const bf16x8*)&Ps[w][(ni * 16 + lm) * PSTR + ks2 * 32 + q4 * 8];
        Ol[ni] = __builtin_amdgcn_mfma_f32_16x16x32_bf16(pf[ni], onesb, Ol[ni], 0, 0, 0);
      }
#pragma unroll
      for (int vi = 0; vi < 8; ++vi) {
        bf16x8 vf = *(const bf16x8*)&Vs[(vi * 16 + lm) * 64 +
                                        (((ks2 * 4 + q4) ^ (lm & 7)) << 3)];
#pragma unroll
        for (int ni = 0; ni < 2; ++ni)
          O[vi][ni] = __builtin_amdgcn_mfma_f32_16x16x32_bf16(
              pf[ni], vf, O[vi][ni], 0, 0, 0);
      }
    }
  }

  // ---- epilogue: rows q = qbase + ni*16 + q4*4+reg match Ol regs exactly --
#pragma unroll
  for (int ni = 0; ni < 2; ++ni) {
#pragma unroll
    for (int reg = 0; reg < 4; ++reg) {
      float invl = 1.0f / Ol[ni][reg];
      size_t orow = ((size_t)b * SS + qbase_row + ni * 16 + q4 * 4 + reg) *
                        (NHEADS * DKV) +
                    h * DKV;
#pragma unroll
      for (int vi = 0; vi < 8; ++vi)
        out[orow + vi * 16 + lm] = f2bf(O[vi][ni][reg] * invl);
    }
  }
}

// ================= launch =================================================
extern "C" void kernel_launch(void* const* d_in, const int* in_sizes, int n_in,
                              void* d_out, int out_size, void* d_ws, size_t ws_size,
                              hipStream_t stream) {
  const float* q_in = (const float*)d_in[0];
  const float* k_in = (const float*)d_in[1];
  const float* v_in = (const float*)d_in[2];
  const unsigned char* mask = (const unsigned char*)d_in[3];
  const float* Wq = (const float*)d_in[4];
  const float* bq = (const float*)d_in[5];
  const float* Wk = (const float*)d_in[6];
  const float* bk = (const float*)d_in[7];
  const float* Wv = (const float*)d_in[8];
  const float* bv = (const float*)d_in[9];
  const float* Wo = (const float*)d_in[10];
  const float* bo = (const float*)d_in[11];

  const int M = BB * SS;  // 4096
  short* Wqt = (short*)d_ws;                   // [2048][2048]
  short* Wot = Wqt + (size_t)DD * DD;          // [2048][2048]
  short* Wkt = Wot + (size_t)DD * DD;          // [128][2048]
  short* Wvt = Wkt + (size_t)DKV * DD;         // [128][2048]
  short* qb  = Wvt + (size_t)DKV * DD;         // [4096][2048] bf16 (input)
  short* qp  = qb + (size_t)M * DD;            // [4096][2048] bf16 (Q proj)
  short* kp  = qp + (size_t)M * DD;            // [4096][128] bf16 (roped K)
  short* vtb = kp + (size_t)M * DKV;           // [2][128][2048] bf16 (V^T)
  float* kpart = (float*)(vtb + (size_t)BB * DKV * SS);  // [4][4096][128]
  float* vpart = kpart + (size_t)SPLITK * M * DKV;       // [4][4096][128]
  short* ap = qb;  // alias: qb dead after Q-proj; flash output reuses it

  cvt_q<<<M * DD / (8 * 256), 256, 0, stream>>>(q_in, qb);
  transpose_w<<<dim3(DD / 32, DD / 32), 256, 0, stream>>>(Wq, Wqt, DD, DD);
  transpose_w<<<dim3(DKV / 32, DD / 32), 256, 0, stream>>>(Wk, Wkt, DD, DKV);
  transpose_w<<<dim3(DKV / 32, DD / 32), 256, 0, stream>>>(Wv, Wvt, DD, DKV);
  transpose_w<<<dim3(DD / 32, DD / 32), 256, 0, stream>>>(Wo, Wot, DD, DD);

  gemm_as<1><<<dim3(DD / 128, M / 128, 1), 256, 0, stream>>>(
      qb, Wqt, bq, qp, M, DD, DD, DD, 1);
  gemm_as<0><<<dim3(1, M / 128, SPLITK), 256, 0, stream>>>(
      k_in, Wkt, nullptr, kpart, M, DKV, DD, DD / SPLITK, 2);
  gemm_as<0><<<dim3(1, M / 128, SPLITK), 256, 0, stream>>>(
      v_in, Wvt, nullptr, vpart, M, DKV, DD, DD / SPLITK, 2);
  kv_reduce<<<M / 64, 256, 0, stream>>>(kpart, vpart, bk, bv, kp, vtb);

  flash_kernel<<<dim3(SS / 128, NHEADS, BB), 256, 0, stream>>>(
      qp, kp, vtb, mask, ap);

  gemm_as<1><<<dim3(DD / 128, M / 128, 1), 256, 0, stream>>>(
      ap, Wot, bo, d_out, M, DD, DD, DD, 0);
}